// Round 17
// baseline (1682.293 us; speedup 1.0000x reference)
//
#include <hip/hip_runtime.h>
#include <hip/hip_bf16.h>
#include <math.h>

typedef unsigned short u16;
typedef __attribute__((ext_vector_type(8))) short short8;
typedef __attribute__((ext_vector_type(4))) float f32x4;

__device__ __forceinline__ u16 f2bf(float f) {
  union { float f; unsigned u; } v; v.f = f;
  unsigned r = v.u + 0x7fffu + ((v.u >> 16) & 1u);
  return (u16)(r >> 16);
}

__device__ __forceinline__ void glds16(const u16* g, u16* l) {
  __builtin_amdgcn_global_load_lds(
      (const __attribute__((address_space(1))) void*)g,
      (__attribute__((address_space(3))) void*)l, 16, 0, 0);
}

template<int N> __device__ __forceinline__ void kbar() {
  asm volatile("s_waitcnt vmcnt(%0)" :: "n"(N) : "memory");
  __builtin_amdgcn_s_barrier();
  asm volatile("" ::: "memory");
}
__device__ __forceinline__ void bar2() {
  asm volatile("" ::: "memory");
  __builtin_amdgcn_s_barrier();
  asm volatile("" ::: "memory");
}

// XCD-aware bijective block swizzle (T1): contiguous original ranges -> one
// XCD, so blocks sharing operand panels co-reside in one L2. Requires n%8==0.
__device__ __forceinline__ int swz8(int b, int n) {
  return (b & 7) * (n >> 3) + (b >> 3);
}

// ===========================================================================
// Diffusion body, batch-paired (2 batches share the staged Tpow A-tile).
// ===========================================================================
template<int BM, int BN, int WR, int WC>
__device__ __forceinline__ void diff_body(
    u16* sm, int bx, int by, int bz,
    const u16* __restrict__ Tpow, const u16* __restrict__ zT,
    u16* __restrict__ zout, int ldz, int C, int coff0,
    u16* __restrict__ zdual, int Fdual)
{
  constexpr int BK = 64;
  constexpr int FM = BM / (WR * 16), FN = BN / (WC * 16);
  constexpr int SLOTS = (BM + 2 * BN) * 8;
  constexpr int NS = (SLOTS + 255) / 256;
  constexpr int VMIN = SLOTS / 256;
  constexpr int HALF = (BM + 2 * BN) * BK;
  const int tid = threadIdx.x, lane = tid & 63, wid = tid >> 6;
  const int wr = wid / WC, wc = wid % WC;
  const int l15 = lane & 15, l4 = lane >> 4;
  const int m0 = bx * BM;
  const int y0 = by * BN;
  const int b0 = (bz / 6) * 2, tc = bz % 6;
  const u16* A = Tpow + (long)tc * 262144;
  const int lb = (tid - lane) * 8;

  const u16* gp[NS];
  #pragma unroll
  for (int i = 0; i < NS; i++) {
    int s = tid + i * 256;
    if (s < BM * 8) {
      int row = s >> 3, kc = s & 7;
      gp[i] = A + (long)(m0 + row) * 512 + (kc ^ (row & 7)) * 8;
    } else {
      int s2 = s - BM * 8;
      int q = s2 / (BN * 8), n = (s2 % (BN * 8)) >> 3, kc = s2 & 7;
      gp[i] = zT + (long)(y0 + n) * 16384 + (b0 + q) * 512 + (kc ^ (n & 7)) * 8;
    }
  }

  auto stage = [&](int buf) {
    u16* base = sm + buf * HALF + lb;
    #pragma unroll
    for (int i = 0; i < NS; i++) {
      if (i * 256 + 256 <= SLOTS || tid < SLOTS - i * 256)
        glds16(gp[i], base + i * 2048);
    }
    #pragma unroll
    for (int i = 0; i < NS; i++) gp[i] += BK;
  };

  f32x4 acc[2][FM][FN] = {};
  auto compute = [&](int buf) {
    const u16* smc = sm + buf * HALF;
    #pragma unroll
    for (int kk = 0; kk < 2; kk++) {
      short8 af[FM], bf[2][FN];
      #pragma unroll
      for (int i = 0; i < FM; i++) {
        int ar = wr * FM * 16 + i * 16 + l15;
        af[i] = *(const short8*)&smc[ar * BK + (((kk * 4 + l4) ^ (ar & 7)) << 3)];
      }
      #pragma unroll
      for (int q = 0; q < 2; q++)
        #pragma unroll
        for (int j = 0; j < FN; j++) {
          int br = wc * FN * 16 + j * 16 + l15;
          bf[q][j] = *(const short8*)&smc[BM * BK + q * BN * BK + br * BK +
                                          (((kk * 4 + l4) ^ (br & 7)) << 3)];
        }
      #pragma unroll
      for (int q = 0; q < 2; q++)
        #pragma unroll
        for (int i = 0; i < FM; i++)
          #pragma unroll
          for (int j = 0; j < FN; j++)
            acc[q][i][j] = __builtin_amdgcn_mfma_f32_16x16x32_bf16(af[i], bf[q][j], acc[q][i][j], 0, 0, 0);
    }
  };

  stage(0);
  int cur = 0;
  for (int t = 0; t < 7; t++) {
    stage(cur ^ 1);
    kbar<VMIN>();
    compute(cur);
    bar2();
    cur ^= 1;
  }
  kbar<0>();
  compute(cur);

  const int tC = (1 + tc) * C;
  #pragma unroll
  for (int q = 0; q < 2; q++) {
    #pragma unroll
    for (int i = 0; i < FM; i++) {
      #pragma unroll
      for (int j = 0; j < FN; j++) {
        int node = m0 + wr * FM * 16 + i * 16 + l4 * 4;
        int ch = y0 + wc * FN * 16 + j * 16 + l15;
        #pragma unroll
        for (int rr = 0; rr < 4; rr++) {
          u16 v = f2bf(acc[q][i][j][rr]);
          long r = (long)(b0 + q) * 512 + node + rr;
          zout[r * ldz + tC + coff0 + ch] = v;
          if (Fdual && ch < Fdual) zdual[r * ldz + tC + ch] = v;
        }
      }
    }
  }
}

template<int BM, int BN, int WR, int WC>
__global__ __launch_bounds__(256, 2) void gemm_diff(
    const u16* __restrict__ Tpow, const u16* __restrict__ zT,
    u16* __restrict__ zout, int ldz, int C, int coff0,
    u16* __restrict__ zdual, int Fdual)
{
  __shared__ u16 sm[2 * (BM + 2 * BN) * 64];
  diff_body<BM, BN, WR, WC>(sm, blockIdx.x, blockIdx.y, blockIdx.z,
                            Tpow, zT, zout, ldz, C, coff0, zdual, Fdual);
}

__global__ __launch_bounds__(256, 2) void gdiff2(
    const u16* __restrict__ Tpow,
    const u16* __restrict__ zT1, u16* __restrict__ z1out, int y1sh, int r1cnt,
    const u16* __restrict__ zT0, u16* __restrict__ z0out, u16* __restrict__ z0dual)
{
  __shared__ u16 sm[2 * (128 + 2 * 64) * 64];
  int b = swz8(blockIdx.x, gridDim.x);
  if (b < r1cnt) {
    int bx = b & 3, rem = b >> 2;
    int by = rem & ((1 << y1sh) - 1), bz = rem >> y1sh;
    diff_body<128, 64, 2, 2>(sm, bx, by, bz, Tpow, zT1, z1out, 1792, 256, 0, nullptr, 0);
  } else {
    int b2 = b - r1cnt;
    int bx = b2 & 3, rem = b2 >> 2;
    int by = rem % 3, bz = rem / 3;
    diff_body<128, 48, 4, 1>(sm, bx, by, bz, Tpow, zT0, z0out, 1024, 144, 0, z0dual, 16);
  }
}

__global__ __launch_bounds__(256, 2) void cdiff2(
    const u16* __restrict__ Tpow,
    const u16* __restrict__ zTc1, u16* __restrict__ z1c, int r1cnt,
    const u16* __restrict__ zTc0, u16* __restrict__ z0c)
{
  __shared__ u16 sm[2 * (128 + 2 * 64) * 64];
  int b = swz8(blockIdx.x, gridDim.x);
  if (b < r1cnt) {
    int bx = b & 3, rem = b >> 2;
    int by = rem & 1, bz = rem >> 1;
    diff_body<128, 64, 2, 2>(sm, bx, by, bz, Tpow, zTc1, z1c, 1792, 256, 128, nullptr, 0);
  } else {
    int b2 = b - r1cnt;
    int bx = b2 & 3, rem = b2 >> 2;
    int by = rem & 1, bz = rem >> 1;
    diff_body<128, 64, 2, 2>(sm, bx, by, bz, Tpow, zTc0, z0c, 1024, 144, 16, nullptr, 0);
  }
}

// ===========================================================================
// Gates projection body, m-PAIRED: two 64-row A-subtiles share one W staging.
// ===========================================================================
template<bool SPLIT>
__device__ __forceinline__ void proj_pair_body(
    u16* sm, int mb, int nb,
    const u16* __restrict__ Az, int ldA,
    const u16* __restrict__ t0, int t0ld,
    const u16* __restrict__ W, int K,
    const float* __restrict__ bias, const float* __restrict__ hst,
    u16* __restrict__ zc, int ldzc, int Foff,
    u16* __restrict__ zTc, float* __restrict__ outbuf)
{
  constexpr int BK = 64;
  constexpr int NSA = 4, NSB = 2;            // A rows 0..127, W rows 128..191
  constexpr int HALF = 192 * BK;             // 12288 u16
  const int tid = threadIdx.x, lane = tid & 63, wid = tid >> 6;
  const int wr = wid >> 1, wc = wid & 1;
  const int l15 = lane & 15, l4 = lane >> 4;
  const int m0 = mb * 128;
  const int n0 = nb * 64;
  const int lb = (tid - lane) * 8;

  long aoffA[NSA], aoffT[NSA];
  const u16* wp[NSB];
  #pragma unroll
  for (int i = 0; i < NSA; i++) {
    int s = tid + i * 256;
    int row = s >> 3, kc = s & 7;
    aoffA[i] = (long)(m0 + row) * ldA + (kc ^ (row & 7)) * 8;
    aoffT[i] = (long)(m0 + row) * t0ld + (kc ^ (row & 7)) * 8;
  }
  #pragma unroll
  for (int i = 0; i < NSB; i++) {
    int s = tid + (NSA + i) * 256;
    int row = s >> 3, kc = s & 7;             // 128..191
    wp[i] = W + (long)(n0 + row - 128) * K + (kc ^ (row & 7)) * 8;
  }

  auto stage = [&](int buf, int koff) {
    u16* base = sm + buf * HALF + lb;
    #pragma unroll
    for (int i = 0; i < NSA; i++) {
      const u16* src = (SPLIT && koff < 256) ? t0 + aoffT[i] + koff
                                             : Az + aoffA[i] + koff;
      glds16(src, base + i * 2048);
    }
    #pragma unroll
    for (int i = 0; i < NSB; i++) { glds16(wp[i], base + (NSA + i) * 2048); wp[i] += BK; }
  };

  f32x4 acc[2][2][2] = {};
  auto compute = [&](int buf) {
    const u16* smc = sm + buf * HALF;
    #pragma unroll
    for (int kk = 0; kk < 2; kk++) {
      short8 af[2][2], bf[2];
      #pragma unroll
      for (int q = 0; q < 2; q++)
        #pragma unroll
        for (int i = 0; i < 2; i++) {
          int ar = q * 64 + wr * 32 + i * 16 + l15;
          af[q][i] = *(const short8*)&smc[ar * BK + (((kk * 4 + l4) ^ (ar & 7)) << 3)];
        }
      #pragma unroll
      for (int j = 0; j < 2; j++) {
        int br = 128 + wc * 32 + j * 16 + l15;
        bf[j] = *(const short8*)&smc[br * BK + (((kk * 4 + l4) ^ (br & 7)) << 3)];
      }
      #pragma unroll
      for (int q = 0; q < 2; q++)
        #pragma unroll
        for (int i = 0; i < 2; i++)
          #pragma unroll
          for (int j = 0; j < 2; j++)
            acc[q][i][j] = __builtin_amdgcn_mfma_f32_16x16x32_bf16(af[q][i], bf[j], acc[q][i][j], 0, 0, 0);
    }
  };

  stage(0, 0);
  int cur = 0;
  const int NT = K >> 6;
  for (int t = 1; t < NT; t++) {
    stage(cur ^ 1, t * 64);
    kbar<6>();
    compute(cur);
    bar2();
    cur ^= 1;
  }
  kbar<0>();
  compute(cur);

  const bool rhpath = (n0 < 128);
  u16 hv16[2][2][2][4];
  #pragma unroll
  for (int q = 0; q < 2; q++)
    #pragma unroll
    for (int i = 0; i < 2; i++)
      #pragma unroll
      for (int j = 0; j < 2; j++) {
        int mbv = m0 + q * 64 + wr * 32 + i * 16 + l4 * 4;
        int n = n0 + wc * 32 + j * 16 + l15;
        #pragma unroll
        for (int rr = 0; rr < 4; rr++) {
          float v = acc[q][i][j][rr] + bias[n];
          long r = mbv + rr;
          float g = 1.f / (1.f + expf(-v));
          if (rhpath) {
            float rh = g * hst[r * 128 + n];
            u16 hv = f2bf(rh);
            zc[r * ldzc + Foff + n] = hv;
            hv16[q][i][j][rr] = hv;
          } else {
            outbuf[r * 128 + (n - 128)] = g;
          }
        }
      }
  if (rhpath) {
    bar2();
    u16* tr = sm;                 // [64 cols][128 rows] swizzled
    #pragma unroll
    for (int q = 0; q < 2; q++)
      #pragma unroll
      for (int i = 0; i < 2; i++)
        #pragma unroll
        for (int j = 0; j < 2; j++) {
          int c = wc * 32 + j * 16 + l15;
          int swz = (c & 7) << 3;
          #pragma unroll
          for (int rr = 0; rr < 4; rr++) {
            int row = q * 64 + wr * 32 + i * 16 + l4 * 4 + rr;
            tr[c * 128 + (row ^ swz)] = hv16[q][i][j][rr];
          }
        }
    __syncthreads();
    int c = tid >> 2, rs = (tid & 3) << 5;
    int swz = (c & 7) << 3;
    long base = (long)(n0 + c) * 16384 + m0 + rs;
    #pragma unroll
    for (int k = 0; k < 4; k++) {
      short8 v = *(const short8*)&tr[c * 128 + ((rs + k * 8) ^ swz)];
      *(short8*)&zTc[base + k * 8] = v;
    }
  }
}

// Merged gates projection: role1 = blocks 0..511 (SPLIT), role0 = 512..1023.
__global__ __launch_bounds__(256, 3) void gproj2(
    const u16* __restrict__ A1, int ldA1, const u16* __restrict__ t01, int t0ld1,
    const u16* __restrict__ W1, int K1,
    const float* __restrict__ b1, const float* __restrict__ h1s,
    u16* __restrict__ zc1, int ldzc1, int Foff1, u16* __restrict__ zT1c, float* __restrict__ ub1,
    const u16* __restrict__ A0, const u16* __restrict__ W0,
    const float* __restrict__ b0, const float* __restrict__ h0s,
    u16* __restrict__ zc0, u16* __restrict__ zT0c, float* __restrict__ ub0)
{
  __shared__ u16 sm[2 * 192 * 64];
  int b = swz8(blockIdx.x, gridDim.x);
  if (b < 512) {
    proj_pair_body<true>(sm, b & 127, b >> 7, A1, ldA1, t01, t0ld1, W1, K1,
                         b1, h1s, zc1, ldzc1, Foff1, zT1c, ub1);
  } else {
    int b2 = b - 512;
    proj_pair_body<false>(sm, b2 & 127, b2 >> 7, A0, 1024, nullptr, 0, W0, 1024,
                          b0, h0s, zc0, 1024, 16, zT0c, ub0);
  }
}

// ===========================================================================
// Fused candidate body (UNPAIRED, BM=32) — used by fused1 only.
// ===========================================================================
__device__ __forceinline__ void cand_body(int blk,
    const u16* __restrict__ Ag, const u16* __restrict__ Ac, int ldA,
    const u16* __restrict__ t0, int t0ld,
    const u16* __restrict__ W, int K,
    const float* __restrict__ bias,
    const float* __restrict__ ub, float* __restrict__ h,
    const float* __restrict__ gamma, const float* __restrict__ beta,
    u16* __restrict__ rm0, int ld0, int co0,
    u16* __restrict__ rm1, int ld1, int co1,
    u16* __restrict__ cm0, int ro0,
    u16* __restrict__ cm1, int ro1,
    const float* __restrict__ xs, int tnext,
    u16* __restrict__ xz0g, u16* __restrict__ xz0c, u16* __restrict__ xz0T,
    u16* sm)
{
  constexpr int BM = 32, BK = 64;
  constexpr int NSA = 1, NSB = 4;
  constexpr int HALF = (32 + 128) * BK;
  const int tid = threadIdx.x, lane = tid & 63, wid = tid >> 6;
  const int wc = wid;
  const int l15 = lane & 15, l4 = lane >> 4;
  const int m0 = blk * BM;
  const int lb = (tid - lane) * 8;

  long aoffA[NSA], aoffT[NSA];
  const u16* wp[NSB];
  #pragma unroll
  for (int i = 0; i < NSA; i++) {
    int s = tid + i * 256;
    int row = s >> 3, kc = s & 7;
    aoffA[i] = (long)(m0 + row) * ldA + (kc ^ (row & 7)) * 8;
    aoffT[i] = (long)(m0 + row) * t0ld + (kc ^ (row & 7)) * 8;
  }
  #pragma unroll
  for (int i = 0; i < NSB; i++) {
    int s = tid + (NSA + i) * 256;
    int row = (s >> 3) - BM, kc = s & 7;
    wp[i] = W + (long)row * K + (kc ^ ((row + BM) & 7)) * 8;
  }

  auto stage = [&](int buf, int koff) {
    u16* base = sm + buf * HALF + lb;
    #pragma unroll
    for (int i = 0; i < NSA; i++) {
      const u16* src;
      if (koff < 128) src = t0 + aoffT[i] + koff;
      else src = (((koff >> 7) & 1) ? Ac : Ag) + aoffA[i] + koff;
      glds16(src, base + i * 2048);
    }
    #pragma unroll
    for (int i = 0; i < NSB; i++) { glds16(wp[i], base + (NSA + i) * 2048); wp[i] += BK; }
  };

  f32x4 acc[2][2] = {};
  auto compute = [&](int buf) {
    const u16* smc = sm + buf * HALF;
    #pragma unroll
    for (int kk = 0; kk < 2; kk++) {
      short8 af[2], bf[2];
      #pragma unroll
      for (int i = 0; i < 2; i++) {
        int ar = i * 16 + l15;
        af[i] = *(const short8*)&smc[ar * BK + (((kk * 4 + l4) ^ (ar & 7)) << 3)];
      }
      #pragma unroll
      for (int j = 0; j < 2; j++) {
        int br = wc * 32 + j * 16 + l15;
        bf[j] = *(const short8*)&smc[BM * BK + br * BK + (((kk * 4 + l4) ^ (br & 7)) << 3)];
      }
      #pragma unroll
      for (int i = 0; i < 2; i++)
        #pragma unroll
        for (int j = 0; j < 2; j++)
          acc[i][j] = __builtin_amdgcn_mfma_f32_16x16x32_bf16(af[i], bf[j], acc[i][j], 0, 0, 0);
    }
  };

  stage(0, 0);
  int cur = 0;
  const int NT = K >> 6;
  for (int t = 1; t < NT; t++) {
    stage(cur ^ 1, t * 64);
    kbar<5>();
    compute(cur);
    bar2();
    cur ^= 1;
  }
  kbar<0>();
  compute(cur);
  __syncthreads();

  float* hs = (float*)sm;
  #pragma unroll
  for (int i = 0; i < 2; i++)
    #pragma unroll
    for (int j = 0; j < 2; j++)
      #pragma unroll
      for (int rr = 0; rr < 4; rr++) {
        int lrow = i * 16 + l4 * 4 + rr;
        int n = wc * 32 + j * 16 + l15;
        long r = m0 + lrow;
        float c = tanhf(acc[i][j][rr] + bias[n]);
        float u = ub[r * 128 + n];
        float hold = h[r * 128 + n];
        hs[lrow * 132 + n] = (1.f - u) * hold + u * c;
      }
  __syncthreads();

  {
    int row = tid >> 3, g = tid & 7;
    float s = 0.f, s2 = 0.f;
    #pragma unroll
    for (int k = 0; k < 16; k++) {
      float v = hs[row * 132 + g + 8 * k];
      s += v; s2 += v * v;
    }
    s += __shfl_xor(s, 1); s2 += __shfl_xor(s2, 1);
    s += __shfl_xor(s, 2); s2 += __shfl_xor(s2, 2);
    s += __shfl_xor(s, 4); s2 += __shfl_xor(s2, 4);
    float mu = s * (1.f / 128.f);
    float var = s2 * (1.f / 128.f) - mu * mu;
    float rs = rsqrtf(var + 1e-5f);
    long rb = (long)(m0 + row) * 128;
    #pragma unroll
    for (int k = 0; k < 16; k++) {
      int c = g + 8 * k;
      float v = (hs[row * 132 + c] - mu) * rs * gamma[c] + beta[c];
      h[rb + c] = v;
      hs[row * 132 + c] = v;
    }
  }
  __syncthreads();

  #pragma unroll
  for (int i = 0; i < 16; i++) {
    int idx = tid + i * 256;
    int row = idx >> 7, c = idx & 127;
    u16 v = f2bf(hs[row * 132 + c]);
    long r = m0 + row;
    rm0[r * ld0 + co0 + c] = v;
    if (rm1) rm1[r * ld1 + co1 + c] = v;
  }
  {
    const int c2 = tid >> 1, half = tid & 1;
    u16 tmp[16];
    #pragma unroll
    for (int i = 0; i < 16; i++) tmp[i] = f2bf(hs[(half * 16 + i) * 132 + c2]);
    const short8* tv = (const short8*)tmp;
    long off = (long)(ro0 + c2) * 16384 + m0 + half * 16;
    *(short8*)&cm0[off] = tv[0];
    *(short8*)&cm0[off + 8] = tv[1];
    if (cm1) {
      long o2 = (long)(ro1 + c2) * 16384 + m0 + half * 16;
      *(short8*)&cm1[o2] = tv[0];
      *(short8*)&cm1[o2 + 8] = tv[1];
    }
  }
  if (xs) {
    for (int e = tid; e < 512; e += 256) {
      int lrow = e >> 4, f = e & 15;
      long r = m0 + lrow;
      int b = (int)(r >> 9), n = (int)(r & 511);
      u16 v = f2bf(xs[(((long)b * 8 + tnext) * 512 + n) * 16 + f]);
      xz0g[r * 1024 + f] = v;
      xz0c[r * 1024 + f] = v;
      xz0T[(long)f * 16384 + r] = v;
    }
  }
}

// ===========================================================================
// Fused candidate body, m-PAIRED: two 32-row A-subtiles share the W staging.
// ===========================================================================
__device__ __forceinline__ void cand_pair_body(int blk,
    const u16* __restrict__ Ag, const u16* __restrict__ Ac, int ldA,
    const u16* __restrict__ t0, int t0ld,
    const u16* __restrict__ W, int K,
    const float* __restrict__ bias,
    const float* __restrict__ ub, float* __restrict__ h,
    const float* __restrict__ gamma, const float* __restrict__ beta,
    u16* __restrict__ rm0, int ld0, int co0,
    u16* __restrict__ rm1, int ld1, int co1,
    u16* __restrict__ cm0, int ro0,
    u16* __restrict__ cm1, int ro1,
    const float* __restrict__ xs, int tnext,
    u16* __restrict__ xz0g, u16* __restrict__ xz0c, u16* __restrict__ xz0T,
    u16* sm)
{
  constexpr int BK = 64;
  constexpr int NSA = 2, NSB = 4;
  constexpr int HALF = 192 * BK;
  const int tid = threadIdx.x, lane = tid & 63, wid = tid >> 6;
  const int wc = wid;
  const int l15 = lane & 15, l4 = lane >> 4;
  const int m0 = blk * 64;
  const int lb = (tid - lane) * 8;

  long aoffA[NSA], aoffT[NSA];
  const u16* wp[NSB];
  #pragma unroll
  for (int i = 0; i < NSA; i++) {
    int s = tid + i * 256;
    int row = s >> 3, kc = s & 7;
    aoffA[i] = (long)(m0 + row) * ldA + (kc ^ (row & 7)) * 8;
    aoffT[i] = (long)(m0 + row) * t0ld + (kc ^ (row & 7)) * 8;
  }
  #pragma unroll
  for (int i = 0; i < NSB; i++) {
    int s = tid + (NSA + i) * 256;
    int row = s >> 3, kc = s & 7;
    wp[i] = W + (long)(row - 64) * K + (kc ^ (row & 7)) * 8;
  }

  auto stage = [&](int buf, int koff) {
    u16* base = sm + buf * HALF + lb;
    #pragma unroll
    for (int i = 0; i < NSA; i++) {
      const u16* src;
      if (koff < 128) src = t0 + aoffT[i] + koff;
      else src = (((koff >> 7) & 1) ? Ac : Ag) + aoffA[i] + koff;
      glds16(src, base + i * 2048);
    }
    #pragma unroll
    for (int i = 0; i < NSB; i++) { glds16(wp[i], base + (NSA + i) * 2048); wp[i] += BK; }
  };

  f32x4 acc[2][2][2] = {};
  auto compute = [&](int buf) {
    const u16* smc = sm + buf * HALF;
    #pragma unroll
    for (int kk = 0; kk < 2; kk++) {
      short8 af[2][2], bf[2];
      #pragma unroll
      for (int q = 0; q < 2; q++)
        #pragma unroll
        for (int i = 0; i < 2; i++) {
          int ar = q * 32 + i * 16 + l15;
          af[q][i] = *(const short8*)&smc[ar * BK + (((kk * 4 + l4) ^ (ar & 7)) << 3)];
        }
      #pragma unroll
      for (int j = 0; j < 2; j++) {
        int br = 64 + wc * 32 + j * 16 + l15;
        bf[j] = *(const short8*)&smc[br * BK + (((kk * 4 + l4) ^ (br & 7)) << 3)];
      }
      #pragma unroll
      for (int q = 0; q < 2; q++)
        #pragma unroll
        for (int i = 0; i < 2; i++)
          #pragma unroll
          for (int j = 0; j < 2; j++)
            acc[q][i][j] = __builtin_amdgcn_mfma_f32_16x16x32_bf16(af[q][i], bf[j], acc[q][i][j], 0, 0, 0);
    }
  };

  stage(0, 0);
  int cur = 0;
  const int NT = K >> 6;
  for (int t = 1; t < NT; t++) {
    stage(cur ^ 1, t * 64);
    kbar<6>();
    compute(cur);
    bar2();
    cur ^= 1;
  }
  kbar<0>();
  compute(cur);
  __syncthreads();

  float* hs = (float*)sm;
  #pragma unroll
  for (int q = 0; q < 2; q++)
    #pragma unroll
    for (int i = 0; i < 2; i++)
      #pragma unroll
      for (int j = 0; j < 2; j++)
        #pragma unroll
        for (int rr = 0; rr < 4; rr++) {
          int lrow = q * 32 + i * 16 + l4 * 4 + rr;
          int n = wc * 32 + j * 16 + l15;
          long r = m0 + lrow;
          float c = tanhf(acc[q][i][j][rr] + bias[n]);
          float u = ub[r * 128 + n];
          float hold = h[r * 128 + n];
          hs[lrow * 132 + n] = (1.f - u) * hold + u * c;
        }
  __syncthreads();

  {
    int row = tid >> 2, g = tid & 3;
    float s = 0.f, s2 = 0.f;
    #pragma unroll
    for (int k = 0; k < 32; k++) {
      float v = hs[row * 132 + g + 4 * k];
      s += v; s2 += v * v;
    }
    s += __shfl_xor(s, 1); s2 += __shfl_xor(s2, 1);
    s += __shfl_xor(s, 2); s2 += __shfl_xor(s2, 2);
    float mu = s * (1.f / 128.f);
    float var = s2 * (1.f / 128.f) - mu * mu;
    float rs = rsqrtf(var + 1e-5f);
    long rb = (long)(m0 + row) * 128;
    #pragma unroll
    for (int k = 0; k < 32; k++) {
      int c = g + 4 * k;
      float v = (hs[row * 132 + c] - mu) * rs * gamma[c] + beta[c];
      h[rb + c] = v;
      hs[row * 132 + c] = v;
    }
  }
  __syncthreads();

  #pragma unroll
  for (int i = 0; i < 32; i++) {
    int idx = tid + i * 256;
    int row = idx >> 7, c = idx & 127;
    u16 v = f2bf(hs[row * 132 + c]);
    long r = m0 + row;
    rm0[r * ld0 + co0 + c] = v;
    if (rm1) rm1[r * ld1 + co1 + c] = v;
  }
  {
    const int c2 = tid >> 1, half = tid & 1;
    u16 tmp[32];
    #pragma unroll
    for (int i = 0; i < 32; i++) tmp[i] = f2bf(hs[(half * 32 + i) * 132 + c2]);
    const short8* tv = (const short8*)tmp;
    long off = (long)(ro0 + c2) * 16384 + m0 + half * 32;
    #pragma unroll
    for (int qq = 0; qq < 4; qq++) *(short8*)&cm0[off + qq * 8] = tv[qq];
    if (cm1) {
      long o2 = (long)(ro1 + c2) * 16384 + m0 + half * 32;
      #pragma unroll
      for (int qq = 0; qq < 4; qq++) *(short8*)&cm1[o2 + qq * 8] = tv[qq];
    }
  }
  if (xs) {
    for (int e = tid; e < 1024; e += 256) {
      int lrow = e >> 4, f = e & 15;
      long r = m0 + lrow;
      int b = (int)(r >> 9), n = (int)(r & 511);
      u16 v = f2bf(xs[(((long)b * 8 + tnext) * 512 + n) * 16 + f]);
      xz0g[r * 1024 + f] = v;
      xz0c[r * 1024 + f] = v;
      xz0T[(long)f * 16384 + r] = v;
    }
  }
}

__global__ __launch_bounds__(256, 4) void fused1(
    const u16* Ag, const u16* Ac, int ldA, const u16* t0, int t0ld,
    const u16* W, int K, const float* bias,
    const float* ub, float* h, const float* gamma, const float* beta,
    u16* rm0, int ld0, int co0, u16* rm1, int ld1, int co1,
    u16* cm0, int ro0, u16* cm1, int ro1,
    const float* xs, int tnext, u16* xz0g, u16* xz0c, u16* xz0T)
{
  __shared__ u16 sm[2 * (32 + 128) * 64];
  cand_body(blockIdx.x, Ag, Ac, ldA, t0, t0ld, W, K, bias, ub, h, gamma, beta,
            rm0, ld0, co0, rm1, ld1, co1, cm0, ro0, cm1, ro1,
            xs, tnext, xz0g, xz0c, xz0T, sm);
}

// Merged fused (PAIRED): blocks 0..255 = role1 (L1f step s), 256..511 = role0.
__global__ __launch_bounds__(256, 3) void fused2(
    const u16* Ag1, const u16* Ac1, int ldA1, const u16* t01, int t0ld1,
    const u16* W1, int K1, const float* bias1,
    const float* ub1, float* h1p, const float* g1p, const float* be1p,
    u16* rm01, int ld01, int co01, u16* cm01, int ro01,
    const u16* A0, const u16* t00, const u16* W0, const float* bias0,
    const float* ub0, float* h0p, const float* g0p, const float* be0p,
    u16* rm00, int co00, u16* rm10, int ld10, int co10,
    u16* cm00, int ro00, u16* cm10, int ro10,
    const float* xs, int tnext, u16* xz0g, u16* xz0c, u16* xz0T)
{
  __shared__ u16 sm[2 * 192 * 64];
  int b = swz8(blockIdx.x, gridDim.x);
  if (b < 256) {
    cand_pair_body(b, Ag1, Ac1, ldA1, t01, t0ld1, W1, K1, bias1, ub1, h1p, g1p, be1p,
                   rm01, ld01, co01, nullptr, 0, 0, cm01, ro01, nullptr, 0,
                   nullptr, 0, nullptr, nullptr, nullptr, sm);
  } else {
    cand_pair_body(b - 256, A0, A0, 1024, t00, 1024, W0, 1024, bias0, ub0, h0p, g0p, be0p,
                   rm00, 1024, co00, rm10, ld10, co10, cm00, ro00, cm10, ro10,
                   xs, tnext, xz0g, xz0c, xz0T, sm);
  }
}

// ===========================================================================
// small helpers
// ===========================================================================
__global__ __launch_bounds__(256) void xk(
    const float* __restrict__ xs, int t,
    u16* __restrict__ z0g, u16* __restrict__ z0c, u16* __restrict__ z0Tg)
{
  int r = blockIdx.x * 256 + threadIdx.x;
  int b = r >> 9, n = r & 511;
  const float* src = xs + (((long)b * 8 + t) * 512 + n) * 16;
  u16 tmp[16];
  #pragma unroll
  for (int f = 0; f < 16; f++) tmp[f] = f2bf(src[f]);
  const short8* tv = (const short8*)tmp;
  *(short8*)&z0g[(long)r * 1024] = tv[0];
  *(short8*)&z0g[(long)r * 1024 + 8] = tv[1];
  *(short8*)&z0c[(long)r * 1024] = tv[0];
  *(short8*)&z0c[(long)r * 1024 + 8] = tv[1];
  #pragma unroll
  for (int f = 0; f < 16; f++) z0Tg[(long)f * 16384 + r] = tmp[f];
}

__global__ void cvtT(const float* __restrict__ Tf, const float* __restrict__ Tb,
                     u16* __restrict__ Tpow, u16* __restrict__ TfT, u16* __restrict__ TbT)
{
  int idx = blockIdx.x * 256 + threadIdx.x;
  int i = idx >> 9, j = idx & 511;
  const float* s = blockIdx.y ? Tb : Tf;
  u16* d = Tpow + (blockIdx.y ? 3 : 0) * 262144;
  u16* dT = blockIdx.y ? TbT : TfT;
  u16 v = f2bf(s[idx]);
  d[idx] = v;
  dT[(long)j * 512 + i] = v;
}

__global__ __launch_bounds__(256) void gemm_pow(
    const u16* __restrict__ A0, const u16* __restrict__ B0, u16* __restrict__ C0,
    const u16* __restrict__ A1, const u16* __restrict__ B1, u16* __restrict__ C1)
{
  constexpr int BM = 64, BN = 64, BK = 32;
  __shared__ u16 sm[(BM + BN) * BK];
  const int tid = threadIdx.x, lane = tid & 63, wid = tid >> 6;
  const int wr = wid >> 1, wc = wid & 1;
  const int l15 = lane & 15, l4 = lane >> 4;
  const int m0 = blockIdx.x * BM, n0 = blockIdx.y * BN;
  const u16* A = blockIdx.z ? A1 : A0;
  const u16* Bt = blockIdx.z ? B1 : B0;
  u16* Cc = blockIdx.z ? C1 : C0;

  f32x4 acc[2][2] = {};
  for (int k0 = 0; k0 < 512; k0 += BK) {
    for (int s = tid; s < (BM + BN) * 4; s += 256) {
      const u16* gp;
      if (s < BM * 4) { int m = s >> 2, kc = s & 3; gp = A + (long)(m0 + m) * 512 + k0 + kc * 8; }
      else { int q = s - BM * 4; int n = q >> 2, kc = q & 3; gp = Bt + (long)(n0 + n) * 512 + k0 + kc * 8; }
      glds16(gp, sm + (s - lane) * 8);
    }
    __syncthreads();
    short8 af[2], bf[2];
    #pragma unroll
    for (int i = 0; i < 2; i++)
      af[i] = *(const short8*)&sm[(wr * 32 + i * 16 + l15) * BK + l4 * 8];
    #pragma unroll
    for (int j = 0; j < 2; j++)
      bf[j] = *(const short8*)&sm[BM * BK + (wc * 32 + j * 16 + l15) * BK + l4 * 8];
    #pragma unroll
    for (int i = 0; i < 2; i++)
      #pragma unroll
      for (int j = 0; j < 2; j++)
        acc[i][j] = __builtin_amdgcn_mfma_f32_16x16x32_bf16(af[i], bf[j], acc[i][j], 0, 0, 0);
    __syncthreads();
  }
  #pragma unroll
  for (int i = 0; i < 2; i++)
    #pragma unroll
    for (int j = 0; j < 2; j++) {
      int mb = m0 + wr * 32 + i * 16 + l4 * 4;
      int n = n0 + wc * 32 + j * 16 + l15;
      #pragma unroll
      for (int rr = 0; rr < 4; rr++)
        Cc[(long)(mb + rr) * 512 + n] = f2bf(acc[i][j][rr]);
    }
}

__global__ void wt_cvt(const float* __restrict__ W, u16* __restrict__ Wt,
                       int Ksrc, int Kpad, int Nout) {
  long idx = (long)blockIdx.x * 256 + threadIdx.x;
  if (idx >= (long)Nout * Kpad) return;
  int o = (int)(idx / Kpad), k = (int)(idx % Kpad);
  Wt[idx] = f2bf(k < Ksrc ? W[(long)k * Nout + o] : 0.f);
}

// ===========================================================================
extern "C" void kernel_launch(void* const* d_in, const int* in_sizes, int n_in,
                              void* d_out, int out_size, void* d_ws, size_t ws_size,
                              hipStream_t stream) {
  const float* x_seq = (const float*)d_in[0];
  const float* Tf  = (const float*)d_in[1];
  const float* Tb  = (const float*)d_in[2];
  const float* Wg0 = (const float*)d_in[3];
  const float* bg0 = (const float*)d_in[4];
  const float* Wc0 = (const float*)d_in[5];
  const float* bc0 = (const float*)d_in[6];
  const float* g0  = (const float*)d_in[7];
  const float* be0 = (const float*)d_in[8];
  const float* Wg1 = (const float*)d_in[9];
  const float* bg1 = (const float*)d_in[10];
  const float* Wc1 = (const float*)d_in[11];
  const float* bc1 = (const float*)d_in[12];
  const float* g1  = (const float*)d_in[13];
  const float* be1 = (const float*)d_in[14];

  constexpr long M = 16384;

  char* p = (char*)d_ws;
  auto carve = [&](size_t bytes) { char* r = p; p += (bytes + 255) & ~(size_t)255; return r; };
  u16* z0g  = (u16*)carve(M * 1024 * 2);
  u16* z0c  = (u16*)carve(M * 1024 * 2);
  u16* z1g  = (u16*)carve(M * 1792 * 2);
  u16* z1c  = (u16*)carve(M * 1792 * 2);
  u16* t0A  = (u16*)carve(M * 256 * 2);
  u16* t0B  = (u16*)carve(M * 256 * 2);
  u16* z0Tg = (u16*)carve(144L * M * 2);
  u16* z0Tc = (u16*)carve(128L * M * 2);
  u16* z1Tg = (u16*)carve(256L * M * 2);
  u16* z1Tc = (u16*)carve(128L * M * 2);
  float* ubuf0 = (float*)carve(M * 128 * 4);
  float* ubuf1 = (float*)carve(M * 128 * 4);
  u16* Tpow = (u16*)carve(6L * 512 * 512 * 2);
  u16* TfT  = (u16*)carve(512L * 512 * 2);
  u16* TbT  = (u16*)carve(512L * 512 * 2);
  u16* Wg0t = (u16*)carve(256L * 1024 * 2);
  u16* Wc0t = (u16*)carve(128L * 1024 * 2);
  u16* Wg1t = (u16*)carve(256L * 1792 * 2);
  u16* Wc1t = (u16*)carve(128L * 1792 * 2);

  float* h0 = (float*)d_out;
  float* h1 = h0 + M * 128;

  hipMemsetAsync(d_out, 0, (size_t)out_size * 4, stream);
  hipMemsetAsync(z0g, 0, (size_t)((char*)(t0B + M * 256) - (char*)z0g), stream);
  hipMemsetAsync(z0Tg + 16L * M, 0, 128L * M * 2, stream);
  hipMemsetAsync(z1Tg + 128L * M, 0, 128L * M * 2, stream);

  cvtT<<<dim3(1024, 2), 256, 0, stream>>>(Tf, Tb, Tpow, TfT, TbT);
  gemm_pow<<<dim3(8, 8, 2), 256, 0, stream>>>(
      Tpow, TfT, Tpow + 1L * 262144, Tpow + 3L * 262144, TbT, Tpow + 4L * 262144);
  gemm_pow<<<dim3(8, 8, 2), 256, 0, stream>>>(
      Tpow + 1L * 262144, TfT, Tpow + 2L * 262144, Tpow + 4L * 262144, TbT, Tpow + 5L * 262144);
  wt_cvt<<<(256 * 1024 + 255) / 256, 256, 0, stream>>>(Wg0, Wg0t, 1008, 1024, 256);
  wt_cvt<<<(128 * 1024 + 255) / 256, 256, 0, stream>>>(Wc0, Wc0t, 1008, 1024, 128);
  wt_cvt<<<(256 * 1792 + 255) / 256, 256, 0, stream>>>(Wg1, Wg1t, 1792, 1792, 256);
  wt_cvt<<<(128 * 1792 + 255) / 256, 256, 0, stream>>>(Wc1, Wc1t, 1792, 1792, 128);

  // ---- prologue: L0 phase of step 0 ----
  xk<<<64, 256, 0, stream>>>(x_seq, 0, z0g, z0c, z0Tg);
  gemm_diff<128, 16, 4, 1><<<dim3(4, 1, 96), 256, 0, stream>>>(
      Tpow, z0Tg, z0g, 1024, 144, 0, z0c, 16);
  gproj2<<<512, 256, 0, stream>>>(                  // role1 slot = L0 gproj(0)
      z0g, 1024, z0g, 1024, Wg0t, 1024, bg0, h0, z0c, 1024, 16, z0Tc, ubuf0,
      z0g, Wg0t, bg0, h0, z0c, z0Tc, ubuf0);
  fused1<<<512, 256, 0, stream>>>(                   // L0f(0): h0(0) -> z0g+16, t0A+0
      z0c, z0c, 1024, z0c, 1024, Wc0t, 1024, bc0, ubuf0, h0, g0, be0,
      z0g, 1024, 16, t0A, 256, 0, z0Tg, 16, z1Tg, 0,
      x_seq, 1, z0g, z0c, z0Tg);

  // ---- skewed pipeline: iter s runs L1(s) merged with L0(s+1) ----
  for (int s = 0; s < 7; s++) {
    u16* t0c = (s & 1) ? t0B : t0A;
    u16* t0n = (s & 1) ? t0A : t0B;
    int y1sh = (s == 0) ? 1 : 2;
    int r1 = 4 * (1 << y1sh) * 96;
    gdiff2<<<r1 + 1152, 256, 0, stream>>>(
        Tpow, z1Tg, z1g, y1sh, r1, z0Tg, z0g, z0c);
    gproj2<<<1024, 256, 0, stream>>>(
        z1g, 1792, t0c, 256, Wg1t, 1792, bg1, h1, z1c, 1792, 128, z1Tc, ubuf1,
        z0g, Wg0t, bg0, h0, z0c, z0Tc, ubuf0);
    int c1 = (s == 0) ? 0 : 768;
    cdiff2<<<c1 + 768, 256, 0, stream>>>(
        Tpow, z1Tc, z1c, c1, z0Tc, z0c);
    fused2<<<512, 256, 0, stream>>>(
        z1g, z1c, 1792, t0c, 256, Wc1t, 1792, bc1, ubuf1, h1, g1, be1,
        t0n, 256, 128, z1Tg, 128,
        z0c, z0c, Wc0t, bc0, ubuf0, h0, g0, be0,
        z0g, 16, t0n, 256, 0, z0Tg, 16, z1Tg, 0,
        (s + 2 <= 7) ? x_seq : nullptr, s + 2, z0g, z0c, z0Tg);
  }

  // ---- epilogue: L1 phase of step 7 ----
  {
    u16* t0c = t0B;   // 7&1 = 1
    u16* t0n = t0A;
    gdiff2<<<1536, 256, 0, stream>>>(Tpow, z1Tg, z1g, 2, 1536, z0Tg, z0g, z0c);
    gproj2<<<512, 256, 0, stream>>>(
        z1g, 1792, t0c, 256, Wg1t, 1792, bg1, h1, z1c, 1792, 128, z1Tc, ubuf1,
        z0g, Wg0t, bg0, h0, z0c, z0Tc, ubuf0);
    cdiff2<<<768, 256, 0, stream>>>(Tpow, z1Tc, z1c, 768, z0Tc, z0c);
    fused1<<<512, 256, 0, stream>>>(
        z1g, z1c, 1792, t0c, 256, Wc1t, 1792, bc1, ubuf1, h1, g1, be1,
        t0n, 256, 128, nullptr, 0, 0, z1Tg, 128, nullptr, 0,
        nullptr, 0, nullptr, nullptr, nullptr);
  }
}

// Round 18
// 1316.103 us; speedup vs baseline: 1.2782x; 1.2782x over previous
//
#include <hip/hip_runtime.h>
#include <hip/hip_bf16.h>
#include <math.h>

typedef unsigned short u16;
typedef __attribute__((ext_vector_type(8))) short short8;
typedef __attribute__((ext_vector_type(4))) float f32x4;

__device__ __forceinline__ u16 f2bf(float f) {
  union { float f; unsigned u; } v; v.f = f;
  unsigned r = v.u + 0x7fffu + ((v.u >> 16) & 1u);
  return (u16)(r >> 16);
}

__device__ __forceinline__ void glds16(const u16* g, u16* l) {
  __builtin_amdgcn_global_load_lds(
      (const __attribute__((address_space(1))) void*)g,
      (__attribute__((address_space(3))) void*)l, 16, 0, 0);
}

template<int N> __device__ __forceinline__ void kbar() {
  asm volatile("s_waitcnt vmcnt(%0)" :: "n"(N) : "memory");
  __builtin_amdgcn_s_barrier();
  asm volatile("" ::: "memory");
}
__device__ __forceinline__ void bar2() {
  asm volatile("" ::: "memory");
  __builtin_amdgcn_s_barrier();
  asm volatile("" ::: "memory");
}

// ===========================================================================
// Diffusion body, batch-paired (2 batches share the staged Tpow A-tile).
// ===========================================================================
template<int BM, int BN, int WR, int WC>
__device__ __forceinline__ void diff_body(
    u16* sm, int bx, int by, int bz,
    const u16* __restrict__ Tpow, const u16* __restrict__ zT,
    u16* __restrict__ zout, int ldz, int C, int coff0,
    u16* __restrict__ zdual, int Fdual)
{
  constexpr int BK = 64;
  constexpr int FM = BM / (WR * 16), FN = BN / (WC * 16);
  constexpr int SLOTS = (BM + 2 * BN) * 8;
  constexpr int NS = (SLOTS + 255) / 256;
  constexpr int VMIN = SLOTS / 256;
  constexpr int HALF = (BM + 2 * BN) * BK;
  const int tid = threadIdx.x, lane = tid & 63, wid = tid >> 6;
  const int wr = wid / WC, wc = wid % WC;
  const int l15 = lane & 15, l4 = lane >> 4;
  const int m0 = bx * BM;
  const int y0 = by * BN;
  const int b0 = (bz / 6) * 2, tc = bz % 6;
  const u16* A = Tpow + (long)tc * 262144;
  const int lb = (tid - lane) * 8;

  const u16* gp[NS];
  #pragma unroll
  for (int i = 0; i < NS; i++) {
    int s = tid + i * 256;
    if (s < BM * 8) {
      int row = s >> 3, kc = s & 7;
      gp[i] = A + (long)(m0 + row) * 512 + (kc ^ (row & 7)) * 8;
    } else {
      int s2 = s - BM * 8;
      int q = s2 / (BN * 8), n = (s2 % (BN * 8)) >> 3, kc = s2 & 7;
      gp[i] = zT + (long)(y0 + n) * 16384 + (b0 + q) * 512 + (kc ^ (n & 7)) * 8;
    }
  }

  auto stage = [&](int buf) {
    u16* base = sm + buf * HALF + lb;
    #pragma unroll
    for (int i = 0; i < NS; i++) {
      if (i * 256 + 256 <= SLOTS || tid < SLOTS - i * 256)
        glds16(gp[i], base + i * 2048);
    }
    #pragma unroll
    for (int i = 0; i < NS; i++) gp[i] += BK;
  };

  f32x4 acc[2][FM][FN] = {};
  auto compute = [&](int buf) {
    const u16* smc = sm + buf * HALF;
    #pragma unroll
    for (int kk = 0; kk < 2; kk++) {
      short8 af[FM], bf[2][FN];
      #pragma unroll
      for (int i = 0; i < FM; i++) {
        int ar = wr * FM * 16 + i * 16 + l15;
        af[i] = *(const short8*)&smc[ar * BK + (((kk * 4 + l4) ^ (ar & 7)) << 3)];
      }
      #pragma unroll
      for (int q = 0; q < 2; q++)
        #pragma unroll
        for (int j = 0; j < FN; j++) {
          int br = wc * FN * 16 + j * 16 + l15;
          bf[q][j] = *(const short8*)&smc[BM * BK + q * BN * BK + br * BK +
                                          (((kk * 4 + l4) ^ (br & 7)) << 3)];
        }
      #pragma unroll
      for (int q = 0; q < 2; q++)
        #pragma unroll
        for (int i = 0; i < FM; i++)
          #pragma unroll
          for (int j = 0; j < FN; j++)
            acc[q][i][j] = __builtin_amdgcn_mfma_f32_16x16x32_bf16(af[i], bf[q][j], acc[q][i][j], 0, 0, 0);
    }
  };

  stage(0);
  int cur = 0;
  for (int t = 0; t < 7; t++) {
    stage(cur ^ 1);
    kbar<VMIN>();
    compute(cur);
    bar2();
    cur ^= 1;
  }
  kbar<0>();
  compute(cur);

  const int tC = (1 + tc) * C;
  #pragma unroll
  for (int q = 0; q < 2; q++) {
    #pragma unroll
    for (int i = 0; i < FM; i++) {
      #pragma unroll
      for (int j = 0; j < FN; j++) {
        int node = m0 + wr * FM * 16 + i * 16 + l4 * 4;
        int ch = y0 + wc * FN * 16 + j * 16 + l15;
        #pragma unroll
        for (int rr = 0; rr < 4; rr++) {
          u16 v = f2bf(acc[q][i][j][rr]);
          long r = (long)(b0 + q) * 512 + node + rr;
          zout[r * ldz + tC + coff0 + ch] = v;
          if (Fdual && ch < Fdual) zdual[r * ldz + tC + ch] = v;
        }
      }
    }
  }
}

template<int BM, int BN, int WR, int WC>
__global__ __launch_bounds__(256, 2) void gemm_diff(
    const u16* __restrict__ Tpow, const u16* __restrict__ zT,
    u16* __restrict__ zout, int ldz, int C, int coff0,
    u16* __restrict__ zdual, int Fdual)
{
  __shared__ u16 sm[2 * (BM + 2 * BN) * 64];
  diff_body<BM, BN, WR, WC>(sm, blockIdx.x, blockIdx.y, blockIdx.z,
                            Tpow, zT, zout, ldz, C, coff0, zdual, Fdual);
}

__global__ __launch_bounds__(256, 2) void gdiff2(
    const u16* __restrict__ Tpow,
    const u16* __restrict__ zT1, u16* __restrict__ z1out, int y1sh, int r1cnt,
    const u16* __restrict__ zT0, u16* __restrict__ z0out, u16* __restrict__ z0dual)
{
  __shared__ u16 sm[2 * (128 + 2 * 64) * 64];
  int b = blockIdx.x;
  if (b < r1cnt) {
    int bx = b & 3, rem = b >> 2;
    int by = rem & ((1 << y1sh) - 1), bz = rem >> y1sh;
    diff_body<128, 64, 2, 2>(sm, bx, by, bz, Tpow, zT1, z1out, 1792, 256, 0, nullptr, 0);
  } else {
    int b2 = b - r1cnt;
    int bx = b2 & 3, rem = b2 >> 2;
    int by = rem % 3, bz = rem / 3;
    diff_body<128, 48, 4, 1>(sm, bx, by, bz, Tpow, zT0, z0out, 1024, 144, 0, z0dual, 16);
  }
}

__global__ __launch_bounds__(256, 2) void cdiff2(
    const u16* __restrict__ Tpow,
    const u16* __restrict__ zTc1, u16* __restrict__ z1c, int r1cnt,
    const u16* __restrict__ zTc0, u16* __restrict__ z0c)
{
  __shared__ u16 sm[2 * (128 + 2 * 64) * 64];
  int b = blockIdx.x;
  if (b < r1cnt) {
    int bx = b & 3, rem = b >> 2;
    int by = rem & 1, bz = rem >> 1;
    diff_body<128, 64, 2, 2>(sm, bx, by, bz, Tpow, zTc1, z1c, 1792, 256, 128, nullptr, 0);
  } else {
    int b2 = b - r1cnt;
    int bx = b2 & 3, rem = b2 >> 2;
    int by = rem & 1, bz = rem >> 1;
    diff_body<128, 64, 2, 2>(sm, bx, by, bz, Tpow, zTc0, z0c, 1024, 144, 16, nullptr, 0);
  }
}

// ===========================================================================
// Gates projection body, m-PAIRED: two 64-row A-subtiles share one W staging.
// ===========================================================================
template<bool SPLIT>
__device__ __forceinline__ void proj_pair_body(
    u16* sm, int mb, int nb,
    const u16* __restrict__ Az, int ldA,
    const u16* __restrict__ t0, int t0ld,
    const u16* __restrict__ W, int K,
    const float* __restrict__ bias, const float* __restrict__ hst,
    u16* __restrict__ zc, int ldzc, int Foff,
    u16* __restrict__ zTc, float* __restrict__ outbuf)
{
  constexpr int BK = 64;
  constexpr int NSA = 4, NSB = 2;            // A rows 0..127, W rows 128..191
  constexpr int HALF = 192 * BK;             // 12288 u16
  const int tid = threadIdx.x, lane = tid & 63, wid = tid >> 6;
  const int wr = wid >> 1, wc = wid & 1;
  const int l15 = lane & 15, l4 = lane >> 4;
  const int m0 = mb * 128;
  const int n0 = nb * 64;
  const int lb = (tid - lane) * 8;

  long aoffA[NSA], aoffT[NSA];
  const u16* wp[NSB];
  #pragma unroll
  for (int i = 0; i < NSA; i++) {
    int s = tid + i * 256;
    int row = s >> 3, kc = s & 7;
    aoffA[i] = (long)(m0 + row) * ldA + (kc ^ (row & 7)) * 8;
    aoffT[i] = (long)(m0 + row) * t0ld + (kc ^ (row & 7)) * 8;
  }
  #pragma unroll
  for (int i = 0; i < NSB; i++) {
    int s = tid + (NSA + i) * 256;
    int row = s >> 3, kc = s & 7;             // 128..191
    wp[i] = W + (long)(n0 + row - 128) * K + (kc ^ (row & 7)) * 8;
  }

  auto stage = [&](int buf, int koff) {
    u16* base = sm + buf * HALF + lb;
    #pragma unroll
    for (int i = 0; i < NSA; i++) {
      const u16* src = (SPLIT && koff < 256) ? t0 + aoffT[i] + koff
                                             : Az + aoffA[i] + koff;
      glds16(src, base + i * 2048);
    }
    #pragma unroll
    for (int i = 0; i < NSB; i++) { glds16(wp[i], base + (NSA + i) * 2048); wp[i] += BK; }
  };

  f32x4 acc[2][2][2] = {};
  auto compute = [&](int buf) {
    const u16* smc = sm + buf * HALF;
    #pragma unroll
    for (int kk = 0; kk < 2; kk++) {
      short8 af[2][2], bf[2];
      #pragma unroll
      for (int q = 0; q < 2; q++)
        #pragma unroll
        for (int i = 0; i < 2; i++) {
          int ar = q * 64 + wr * 32 + i * 16 + l15;
          af[q][i] = *(const short8*)&smc[ar * BK + (((kk * 4 + l4) ^ (ar & 7)) << 3)];
        }
      #pragma unroll
      for (int j = 0; j < 2; j++) {
        int br = 128 + wc * 32 + j * 16 + l15;
        bf[j] = *(const short8*)&smc[br * BK + (((kk * 4 + l4) ^ (br & 7)) << 3)];
      }
      #pragma unroll
      for (int q = 0; q < 2; q++)
        #pragma unroll
        for (int i = 0; i < 2; i++)
          #pragma unroll
          for (int j = 0; j < 2; j++)
            acc[q][i][j] = __builtin_amdgcn_mfma_f32_16x16x32_bf16(af[q][i], bf[j], acc[q][i][j], 0, 0, 0);
    }
  };

  stage(0, 0);
  int cur = 0;
  const int NT = K >> 6;
  for (int t = 1; t < NT; t++) {
    stage(cur ^ 1, t * 64);
    kbar<6>();
    compute(cur);
    bar2();
    cur ^= 1;
  }
  kbar<0>();
  compute(cur);

  const bool rhpath = (n0 < 128);
  u16 hv16[2][2][2][4];
  #pragma unroll
  for (int q = 0; q < 2; q++)
    #pragma unroll
    for (int i = 0; i < 2; i++)
      #pragma unroll
      for (int j = 0; j < 2; j++) {
        int mbv = m0 + q * 64 + wr * 32 + i * 16 + l4 * 4;
        int n = n0 + wc * 32 + j * 16 + l15;
        #pragma unroll
        for (int rr = 0; rr < 4; rr++) {
          float v = acc[q][i][j][rr] + bias[n];
          long r = mbv + rr;
          float g = 1.f / (1.f + expf(-v));
          if (rhpath) {
            float rh = g * hst[r * 128 + n];
            u16 hv = f2bf(rh);
            zc[r * ldzc + Foff + n] = hv;
            hv16[q][i][j][rr] = hv;
          } else {
            outbuf[r * 128 + (n - 128)] = g;
          }
        }
      }
  if (rhpath) {
    bar2();
    u16* tr = sm;                 // [64 cols][128 rows] swizzled
    #pragma unroll
    for (int q = 0; q < 2; q++)
      #pragma unroll
      for (int i = 0; i < 2; i++)
        #pragma unroll
        for (int j = 0; j < 2; j++) {
          int c = wc * 32 + j * 16 + l15;
          int swz = (c & 7) << 3;
          #pragma unroll
          for (int rr = 0; rr < 4; rr++) {
            int row = q * 64 + wr * 32 + i * 16 + l4 * 4 + rr;
            tr[c * 128 + (row ^ swz)] = hv16[q][i][j][rr];
          }
        }
    __syncthreads();
    int c = tid >> 2, rs = (tid & 3) << 5;
    int swz = (c & 7) << 3;
    long base = (long)(n0 + c) * 16384 + m0 + rs;
    #pragma unroll
    for (int k = 0; k < 4; k++) {
      short8 v = *(const short8*)&tr[c * 128 + ((rs + k * 8) ^ swz)];
      *(short8*)&zTc[base + k * 8] = v;
    }
  }
}

// Merged gates projection: role1 = blocks 0..511 (SPLIT), role0 = 512..1023.
__global__ __launch_bounds__(256, 3) void gproj2(
    const u16* __restrict__ A1, int ldA1, const u16* __restrict__ t01, int t0ld1,
    const u16* __restrict__ W1, int K1,
    const float* __restrict__ b1, const float* __restrict__ h1s,
    u16* __restrict__ zc1, int ldzc1, int Foff1, u16* __restrict__ zT1c, float* __restrict__ ub1,
    const u16* __restrict__ A0, const u16* __restrict__ W0,
    const float* __restrict__ b0, const float* __restrict__ h0s,
    u16* __restrict__ zc0, u16* __restrict__ zT0c, float* __restrict__ ub0)
{
  __shared__ u16 sm[2 * 192 * 64];
  int b = blockIdx.x;
  if (b < 512) {
    proj_pair_body<true>(sm, b & 127, b >> 7, A1, ldA1, t01, t0ld1, W1, K1,
                         b1, h1s, zc1, ldzc1, Foff1, zT1c, ub1);
  } else {
    int b2 = b - 512;
    proj_pair_body<false>(sm, b2 & 127, b2 >> 7, A0, 1024, nullptr, 0, W0, 1024,
                          b0, h0s, zc0, 1024, 16, zT0c, ub0);
  }
}

// ===========================================================================
// Fused candidate body (UNPAIRED, BM=32) — used by fused1 only.
// ===========================================================================
__device__ __forceinline__ void cand_body(int blk,
    const u16* __restrict__ Ag, const u16* __restrict__ Ac, int ldA,
    const u16* __restrict__ t0, int t0ld,
    const u16* __restrict__ W, int K,
    const float* __restrict__ bias,
    const float* __restrict__ ub, float* __restrict__ h,
    const float* __restrict__ gamma, const float* __restrict__ beta,
    u16* __restrict__ rm0, int ld0, int co0,
    u16* __restrict__ rm1, int ld1, int co1,
    u16* __restrict__ cm0, int ro0,
    u16* __restrict__ cm1, int ro1,
    const float* __restrict__ xs, int tnext,
    u16* __restrict__ xz0g, u16* __restrict__ xz0c, u16* __restrict__ xz0T,
    u16* sm)
{
  constexpr int BM = 32, BK = 64;
  constexpr int NSA = 1, NSB = 4;
  constexpr int HALF = (32 + 128) * BK;
  const int tid = threadIdx.x, lane = tid & 63, wid = tid >> 6;
  const int wc = wid;
  const int l15 = lane & 15, l4 = lane >> 4;
  const int m0 = blk * BM;
  const int lb = (tid - lane) * 8;

  long aoffA[NSA], aoffT[NSA];
  const u16* wp[NSB];
  #pragma unroll
  for (int i = 0; i < NSA; i++) {
    int s = tid + i * 256;
    int row = s >> 3, kc = s & 7;
    aoffA[i] = (long)(m0 + row) * ldA + (kc ^ (row & 7)) * 8;
    aoffT[i] = (long)(m0 + row) * t0ld + (kc ^ (row & 7)) * 8;
  }
  #pragma unroll
  for (int i = 0; i < NSB; i++) {
    int s = tid + (NSA + i) * 256;
    int row = (s >> 3) - BM, kc = s & 7;
    wp[i] = W + (long)row * K + (kc ^ ((row + BM) & 7)) * 8;
  }

  auto stage = [&](int buf, int koff) {
    u16* base = sm + buf * HALF + lb;
    #pragma unroll
    for (int i = 0; i < NSA; i++) {
      const u16* src;
      if (koff < 128) src = t0 + aoffT[i] + koff;
      else src = (((koff >> 7) & 1) ? Ac : Ag) + aoffA[i] + koff;
      glds16(src, base + i * 2048);
    }
    #pragma unroll
    for (int i = 0; i < NSB; i++) { glds16(wp[i], base + (NSA + i) * 2048); wp[i] += BK; }
  };

  f32x4 acc[2][2] = {};
  auto compute = [&](int buf) {
    const u16* smc = sm + buf * HALF;
    #pragma unroll
    for (int kk = 0; kk < 2; kk++) {
      short8 af[2], bf[2];
      #pragma unroll
      for (int i = 0; i < 2; i++) {
        int ar = i * 16 + l15;
        af[i] = *(const short8*)&smc[ar * BK + (((kk * 4 + l4) ^ (ar & 7)) << 3)];
      }
      #pragma unroll
      for (int j = 0; j < 2; j++) {
        int br = wc * 32 + j * 16 + l15;
        bf[j] = *(const short8*)&smc[BM * BK + br * BK + (((kk * 4 + l4) ^ (br & 7)) << 3)];
      }
      #pragma unroll
      for (int i = 0; i < 2; i++)
        #pragma unroll
        for (int j = 0; j < 2; j++)
          acc[i][j] = __builtin_amdgcn_mfma_f32_16x16x32_bf16(af[i], bf[j], acc[i][j], 0, 0, 0);
    }
  };

  stage(0, 0);
  int cur = 0;
  const int NT = K >> 6;
  for (int t = 1; t < NT; t++) {
    stage(cur ^ 1, t * 64);
    kbar<5>();
    compute(cur);
    bar2();
    cur ^= 1;
  }
  kbar<0>();
  compute(cur);
  __syncthreads();

  float* hs = (float*)sm;
  #pragma unroll
  for (int i = 0; i < 2; i++)
    #pragma unroll
    for (int j = 0; j < 2; j++)
      #pragma unroll
      for (int rr = 0; rr < 4; rr++) {
        int lrow = i * 16 + l4 * 4 + rr;
        int n = wc * 32 + j * 16 + l15;
        long r = m0 + lrow;
        float c = tanhf(acc[i][j][rr] + bias[n]);
        float u = ub[r * 128 + n];
        float hold = h[r * 128 + n];
        hs[lrow * 132 + n] = (1.f - u) * hold + u * c;
      }
  __syncthreads();

  {
    int row = tid >> 3, g = tid & 7;
    float s = 0.f, s2 = 0.f;
    #pragma unroll
    for (int k = 0; k < 16; k++) {
      float v = hs[row * 132 + g + 8 * k];
      s += v; s2 += v * v;
    }
    s += __shfl_xor(s, 1); s2 += __shfl_xor(s2, 1);
    s += __shfl_xor(s, 2); s2 += __shfl_xor(s2, 2);
    s += __shfl_xor(s, 4); s2 += __shfl_xor(s2, 4);
    float mu = s * (1.f / 128.f);
    float var = s2 * (1.f / 128.f) - mu * mu;
    float rs = rsqrtf(var + 1e-5f);
    long rb = (long)(m0 + row) * 128;
    #pragma unroll
    for (int k = 0; k < 16; k++) {
      int c = g + 8 * k;
      float v = (hs[row * 132 + c] - mu) * rs * gamma[c] + beta[c];
      h[rb + c] = v;
      hs[row * 132 + c] = v;
    }
  }
  __syncthreads();

  #pragma unroll
  for (int i = 0; i < 16; i++) {
    int idx = tid + i * 256;
    int row = idx >> 7, c = idx & 127;
    u16 v = f2bf(hs[row * 132 + c]);
    long r = m0 + row;
    rm0[r * ld0 + co0 + c] = v;
    if (rm1) rm1[r * ld1 + co1 + c] = v;
  }
  {
    const int c2 = tid >> 1, half = tid & 1;
    u16 tmp[16];
    #pragma unroll
    for (int i = 0; i < 16; i++) tmp[i] = f2bf(hs[(half * 16 + i) * 132 + c2]);
    const short8* tv = (const short8*)tmp;
    long off = (long)(ro0 + c2) * 16384 + m0 + half * 16;
    *(short8*)&cm0[off] = tv[0];
    *(short8*)&cm0[off + 8] = tv[1];
    if (cm1) {
      long o2 = (long)(ro1 + c2) * 16384 + m0 + half * 16;
      *(short8*)&cm1[o2] = tv[0];
      *(short8*)&cm1[o2 + 8] = tv[1];
    }
  }
  if (xs) {
    for (int e = tid; e < 512; e += 256) {
      int lrow = e >> 4, f = e & 15;
      long r = m0 + lrow;
      int b = (int)(r >> 9), n = (int)(r & 511);
      u16 v = f2bf(xs[(((long)b * 8 + tnext) * 512 + n) * 16 + f]);
      xz0g[r * 1024 + f] = v;
      xz0c[r * 1024 + f] = v;
      xz0T[(long)f * 16384 + r] = v;
    }
  }
}

// ===========================================================================
// Fused candidate body, m-PAIRED: two 32-row A-subtiles share the W staging.
// ===========================================================================
__device__ __forceinline__ void cand_pair_body(int blk,
    const u16* __restrict__ Ag, const u16* __restrict__ Ac, int ldA,
    const u16* __restrict__ t0, int t0ld,
    const u16* __restrict__ W, int K,
    const float* __restrict__ bias,
    const float* __restrict__ ub, float* __restrict__ h,
    const float* __restrict__ gamma, const float* __restrict__ beta,
    u16* __restrict__ rm0, int ld0, int co0,
    u16* __restrict__ rm1, int ld1, int co1,
    u16* __restrict__ cm0, int ro0,
    u16* __restrict__ cm1, int ro1,
    const float* __restrict__ xs, int tnext,
    u16* __restrict__ xz0g, u16* __restrict__ xz0c, u16* __restrict__ xz0T,
    u16* sm)
{
  constexpr int BK = 64;
  constexpr int NSA = 2, NSB = 4;
  constexpr int HALF = 192 * BK;
  const int tid = threadIdx.x, lane = tid & 63, wid = tid >> 6;
  const int wc = wid;
  const int l15 = lane & 15, l4 = lane >> 4;
  const int m0 = blk * 64;
  const int lb = (tid - lane) * 8;

  long aoffA[NSA], aoffT[NSA];
  const u16* wp[NSB];
  #pragma unroll
  for (int i = 0; i < NSA; i++) {
    int s = tid + i * 256;
    int row = s >> 3, kc = s & 7;
    aoffA[i] = (long)(m0 + row) * ldA + (kc ^ (row & 7)) * 8;
    aoffT[i] = (long)(m0 + row) * t0ld + (kc ^ (row & 7)) * 8;
  }
  #pragma unroll
  for (int i = 0; i < NSB; i++) {
    int s = tid + (NSA + i) * 256;
    int row = s >> 3, kc = s & 7;
    wp[i] = W + (long)(row - 64) * K + (kc ^ (row & 7)) * 8;
  }

  auto stage = [&](int buf, int koff) {
    u16* base = sm + buf * HALF + lb;
    #pragma unroll
    for (int i = 0; i < NSA; i++) {
      const u16* src;
      if (koff < 128) src = t0 + aoffT[i] + koff;
      else src = (((koff >> 7) & 1) ? Ac : Ag) + aoffA[i] + koff;
      glds16(src, base + i * 2048);
    }
    #pragma unroll
    for (int i = 0; i < NSB; i++) { glds16(wp[i], base + (NSA + i) * 2048); wp[i] += BK; }
  };

  f32x4 acc[2][2][2] = {};
  auto compute = [&](int buf) {
    const u16* smc = sm + buf * HALF;
    #pragma unroll
    for (int kk = 0; kk < 2; kk++) {
      short8 af[2][2], bf[2];
      #pragma unroll
      for (int q = 0; q < 2; q++)
        #pragma unroll
        for (int i = 0; i < 2; i++) {
          int ar = q * 32 + i * 16 + l15;
          af[q][i] = *(const short8*)&smc[ar * BK + (((kk * 4 + l4) ^ (ar & 7)) << 3)];
        }
      #pragma unroll
      for (int j = 0; j < 2; j++) {
        int br = 64 + wc * 32 + j * 16 + l15;
        bf[j] = *(const short8*)&smc[br * BK + (((kk * 4 + l4) ^ (br & 7)) << 3)];
      }
      #pragma unroll
      for (int q = 0; q < 2; q++)
        #pragma unroll
        for (int i = 0; i < 2; i++)
          #pragma unroll
          for (int j = 0; j < 2; j++)
            acc[q][i][j] = __builtin_amdgcn_mfma_f32_16x16x32_bf16(af[q][i], bf[j], acc[q][i][j], 0, 0, 0);
    }
  };

  stage(0, 0);
  int cur = 0;
  const int NT = K >> 6;
  for (int t = 1; t < NT; t++) {
    stage(cur ^ 1, t * 64);
    kbar<6>();
    compute(cur);
    bar2();
    cur ^= 1;
  }
  kbar<0>();
  compute(cur);
  __syncthreads();

  float* hs = (float*)sm;
  #pragma unroll
  for (int q = 0; q < 2; q++)
    #pragma unroll
    for (int i = 0; i < 2; i++)
      #pragma unroll
      for (int j = 0; j < 2; j++)
        #pragma unroll
        for (int rr = 0; rr < 4; rr++) {
          int lrow = q * 32 + i * 16 + l4 * 4 + rr;
          int n = wc * 32 + j * 16 + l15;
          long r = m0 + lrow;
          float c = tanhf(acc[q][i][j][rr] + bias[n]);
          float u = ub[r * 128 + n];
          float hold = h[r * 128 + n];
          hs[lrow * 132 + n] = (1.f - u) * hold + u * c;
        }
  __syncthreads();

  {
    int row = tid >> 2, g = tid & 3;
    float s = 0.f, s2 = 0.f;
    #pragma unroll
    for (int k = 0; k < 32; k++) {
      float v = hs[row * 132 + g + 4 * k];
      s += v; s2 += v * v;
    }
    s += __shfl_xor(s, 1); s2 += __shfl_xor(s2, 1);
    s += __shfl_xor(s, 2); s2 += __shfl_xor(s2, 2);
    float mu = s * (1.f / 128.f);
    float var = s2 * (1.f / 128.f) - mu * mu;
    float rs = rsqrtf(var + 1e-5f);
    long rb = (long)(m0 + row) * 128;
    #pragma unroll
    for (int k = 0; k < 32; k++) {
      int c = g + 4 * k;
      float v = (hs[row * 132 + c] - mu) * rs * gamma[c] + beta[c];
      h[rb + c] = v;
      hs[row * 132 + c] = v;
    }
  }
  __syncthreads();

  #pragma unroll
  for (int i = 0; i < 32; i++) {
    int idx = tid + i * 256;
    int row = idx >> 7, c = idx & 127;
    u16 v = f2bf(hs[row * 132 + c]);
    long r = m0 + row;
    rm0[r * ld0 + co0 + c] = v;
    if (rm1) rm1[r * ld1 + co1 + c] = v;
  }
  {
    const int c2 = tid >> 1, half = tid & 1;
    u16 tmp[32];
    #pragma unroll
    for (int i = 0; i < 32; i++) tmp[i] = f2bf(hs[(half * 32 + i) * 132 + c2]);
    const short8* tv = (const short8*)tmp;
    long off = (long)(ro0 + c2) * 16384 + m0 + half * 32;
    #pragma unroll
    for (int qq = 0; qq < 4; qq++) *(short8*)&cm0[off + qq * 8] = tv[qq];
    if (cm1) {
      long o2 = (long)(ro1 + c2) * 16384 + m0 + half * 32;
      #pragma unroll
      for (int qq = 0; qq < 4; qq++) *(short8*)&cm1[o2 + qq * 8] = tv[qq];
    }
  }
  if (xs) {
    for (int e = tid; e < 1024; e += 256) {
      int lrow = e >> 4, f = e & 15;
      long r = m0 + lrow;
      int b = (int)(r >> 9), n = (int)(r & 511);
      u16 v = f2bf(xs[(((long)b * 8 + tnext) * 512 + n) * 16 + f]);
      xz0g[r * 1024 + f] = v;
      xz0c[r * 1024 + f] = v;
      xz0T[(long)f * 16384 + r] = v;
    }
  }
}

__global__ __launch_bounds__(256, 4) void fused1(
    const u16* Ag, const u16* Ac, int ldA, const u16* t0, int t0ld,
    const u16* W, int K, const float* bias,
    const float* ub, float* h, const float* gamma, const float* beta,
    u16* rm0, int ld0, int co0, u16* rm1, int ld1, int co1,
    u16* cm0, int ro0, u16* cm1, int ro1,
    const float* xs, int tnext, u16* xz0g, u16* xz0c, u16* xz0T)
{
  __shared__ u16 sm[2 * (32 + 128) * 64];
  cand_body(blockIdx.x, Ag, Ac, ldA, t0, t0ld, W, K, bias, ub, h, gamma, beta,
            rm0, ld0, co0, rm1, ld1, co1, cm0, ro0, cm1, ro1,
            xs, tnext, xz0g, xz0c, xz0T, sm);
}

// Merged fused (PAIRED): blocks 0..255 = role1 (L1f step s), 256..511 = role0.
__global__ __launch_bounds__(256, 3) void fused2(
    const u16* Ag1, const u16* Ac1, int ldA1, const u16* t01, int t0ld1,
    const u16* W1, int K1, const float* bias1,
    const float* ub1, float* h1p, const float* g1p, const float* be1p,
    u16* rm01, int ld01, int co01, u16* cm01, int ro01,
    const u16* A0, const u16* t00, const u16* W0, const float* bias0,
    const float* ub0, float* h0p, const float* g0p, const float* be0p,
    u16* rm00, int co00, u16* rm10, int ld10, int co10,
    u16* cm00, int ro00, u16* cm10, int ro10,
    const float* xs, int tnext, u16* xz0g, u16* xz0c, u16* xz0T)
{
  __shared__ u16 sm[2 * 192 * 64];
  int b = blockIdx.x;
  if (b < 256) {
    cand_pair_body(b, Ag1, Ac1, ldA1, t01, t0ld1, W1, K1, bias1, ub1, h1p, g1p, be1p,
                   rm01, ld01, co01, nullptr, 0, 0, cm01, ro01, nullptr, 0,
                   nullptr, 0, nullptr, nullptr, nullptr, sm);
  } else {
    cand_pair_body(b - 256, A0, A0, 1024, t00, 1024, W0, 1024, bias0, ub0, h0p, g0p, be0p,
                   rm00, 1024, co00, rm10, ld10, co10, cm00, ro00, cm10, ro10,
                   xs, tnext, xz0g, xz0c, xz0T, sm);
  }
}

// ===========================================================================
// small helpers
// ===========================================================================
__global__ __launch_bounds__(256) void xk(
    const float* __restrict__ xs, int t,
    u16* __restrict__ z0g, u16* __restrict__ z0c, u16* __restrict__ z0Tg)
{
  int r = blockIdx.x * 256 + threadIdx.x;
  int b = r >> 9, n = r & 511;
  const float* src = xs + (((long)b * 8 + t) * 512 + n) * 16;
  u16 tmp[16];
  #pragma unroll
  for (int f = 0; f < 16; f++) tmp[f] = f2bf(src[f]);
  const short8* tv = (const short8*)tmp;
  *(short8*)&z0g[(long)r * 1024] = tv[0];
  *(short8*)&z0g[(long)r * 1024 + 8] = tv[1];
  *(short8*)&z0c[(long)r * 1024] = tv[0];
  *(short8*)&z0c[(long)r * 1024 + 8] = tv[1];
  #pragma unroll
  for (int f = 0; f < 16; f++) z0Tg[(long)f * 16384 + r] = tmp[f];
}

__global__ void cvtT(const float* __restrict__ Tf, const float* __restrict__ Tb,
                     u16* __restrict__ Tpow, u16* __restrict__ TfT, u16* __restrict__ TbT)
{
  int idx = blockIdx.x * 256 + threadIdx.x;
  int i = idx >> 9, j = idx & 511;
  const float* s = blockIdx.y ? Tb : Tf;
  u16* d = Tpow + (blockIdx.y ? 3 : 0) * 262144;
  u16* dT = blockIdx.y ? TbT : TfT;
  u16 v = f2bf(s[idx]);
  d[idx] = v;
  dT[(long)j * 512 + i] = v;
}

__global__ __launch_bounds__(256) void gemm_pow(
    const u16* __restrict__ A0, const u16* __restrict__ B0, u16* __restrict__ C0,
    const u16* __restrict__ A1, const u16* __restrict__ B1, u16* __restrict__ C1)
{
  constexpr int BM = 64, BN = 64, BK = 32;
  __shared__ u16 sm[(BM + BN) * BK];
  const int tid = threadIdx.x, lane = tid & 63, wid = tid >> 6;
  const int wr = wid >> 1, wc = wid & 1;
  const int l15 = lane & 15, l4 = lane >> 4;
  const int m0 = blockIdx.x * BM, n0 = blockIdx.y * BN;
  const u16* A = blockIdx.z ? A1 : A0;
  const u16* Bt = blockIdx.z ? B1 : B0;
  u16* Cc = blockIdx.z ? C1 : C0;

  f32x4 acc[2][2] = {};
  for (int k0 = 0; k0 < 512; k0 += BK) {
    for (int s = tid; s < (BM + BN) * 4; s += 256) {
      const u16* gp;
      if (s < BM * 4) { int m = s >> 2, kc = s & 3; gp = A + (long)(m0 + m) * 512 + k0 + kc * 8; }
      else { int q = s - BM * 4; int n = q >> 2, kc = q & 3; gp = Bt + (long)(n0 + n) * 512 + k0 + kc * 8; }
      glds16(gp, sm + (s - lane) * 8);
    }
    __syncthreads();
    short8 af[2], bf[2];
    #pragma unroll
    for (int i = 0; i < 2; i++)
      af[i] = *(const short8*)&sm[(wr * 32 + i * 16 + l15) * BK + l4 * 8];
    #pragma unroll
    for (int j = 0; j < 2; j++)
      bf[j] = *(const short8*)&sm[BM * BK + (wc * 32 + j * 16 + l15) * BK + l4 * 8];
    #pragma unroll
    for (int i = 0; i < 2; i++)
      #pragma unroll
      for (int j = 0; j < 2; j++)
        acc[i][j] = __builtin_amdgcn_mfma_f32_16x16x32_bf16(af[i], bf[j], acc[i][j], 0, 0, 0);
    __syncthreads();
  }
  #pragma unroll
  for (int i = 0; i < 2; i++)
    #pragma unroll
    for (int j = 0; j < 2; j++) {
      int mb = m0 + wr * 32 + i * 16 + l4 * 4;
      int n = n0 + wc * 32 + j * 16 + l15;
      #pragma unroll
      for (int rr = 0; rr < 4; rr++)
        Cc[(long)(mb + rr) * 512 + n] = f2bf(acc[i][j][rr]);
    }
}

__global__ void wt_cvt(const float* __restrict__ W, u16* __restrict__ Wt,
                       int Ksrc, int Kpad, int Nout) {
  long idx = (long)blockIdx.x * 256 + threadIdx.x;
  if (idx >= (long)Nout * Kpad) return;
  int o = (int)(idx / Kpad), k = (int)(idx % Kpad);
  Wt[idx] = f2bf(k < Ksrc ? W[(long)k * Nout + o] : 0.f);
}

// ===========================================================================
extern "C" void kernel_launch(void* const* d_in, const int* in_sizes, int n_in,
                              void* d_out, int out_size, void* d_ws, size_t ws_size,
                              hipStream_t stream) {
  const float* x_seq = (const float*)d_in[0];
  const float* Tf  = (const float*)d_in[1];
  const float* Tb  = (const float*)d_in[2];
  const float* Wg0 = (const float*)d_in[3];
  const float* bg0 = (const float*)d_in[4];
  const float* Wc0 = (const float*)d_in[5];
  const float* bc0 = (const float*)d_in[6];
  const float* g0  = (const float*)d_in[7];
  const float* be0 = (const float*)d_in[8];
  const float* Wg1 = (const float*)d_in[9];
  const float* bg1 = (const float*)d_in[10];
  const float* Wc1 = (const float*)d_in[11];
  const float* bc1 = (const float*)d_in[12];
  const float* g1  = (const float*)d_in[13];
  const float* be1 = (const float*)d_in[14];

  constexpr long M = 16384;

  char* p = (char*)d_ws;
  auto carve = [&](size_t bytes) { char* r = p; p += (bytes + 255) & ~(size_t)255; return r; };
  u16* z0g  = (u16*)carve(M * 1024 * 2);
  u16* z0c  = (u16*)carve(M * 1024 * 2);
  u16* z1g  = (u16*)carve(M * 1792 * 2);
  u16* z1c  = (u16*)carve(M * 1792 * 2);
  u16* t0A  = (u16*)carve(M * 256 * 2);
  u16* t0B  = (u16*)carve(M * 256 * 2);
  u16* z0Tg = (u16*)carve(144L * M * 2);
  u16* z0Tc = (u16*)carve(128L * M * 2);
  u16* z1Tg = (u16*)carve(256L * M * 2);
  u16* z1Tc = (u16*)carve(128L * M * 2);
  float* ubuf0 = (float*)carve(M * 128 * 4);
  float* ubuf1 = (float*)carve(M * 128 * 4);
  u16* Tpow = (u16*)carve(6L * 512 * 512 * 2);
  u16* TfT  = (u16*)carve(512L * 512 * 2);
  u16* TbT  = (u16*)carve(512L * 512 * 2);
  u16* Wg0t = (u16*)carve(256L * 1024 * 2);
  u16* Wc0t = (u16*)carve(128L * 1024 * 2);
  u16* Wg1t = (u16*)carve(256L * 1792 * 2);
  u16* Wc1t = (u16*)carve(128L * 1792 * 2);

  float* h0 = (float*)d_out;
  float* h1 = h0 + M * 128;

  hipMemsetAsync(d_out, 0, (size_t)out_size * 4, stream);
  hipMemsetAsync(z0g, 0, (size_t)((char*)(t0B + M * 256) - (char*)z0g), stream);
  hipMemsetAsync(z0Tg + 16L * M, 0, 128L * M * 2, stream);
  hipMemsetAsync(z1Tg + 128L * M, 0, 128L * M * 2, stream);

  cvtT<<<dim3(1024, 2), 256, 0, stream>>>(Tf, Tb, Tpow, TfT, TbT);
  gemm_pow<<<dim3(8, 8, 2), 256, 0, stream>>>(
      Tpow, TfT, Tpow + 1L * 262144, Tpow + 3L * 262144, TbT, Tpow + 4L * 262144);
  gemm_pow<<<dim3(8, 8, 2), 256, 0, stream>>>(
      Tpow + 1L * 262144, TfT, Tpow + 2L * 262144, Tpow + 4L * 262144, TbT, Tpow + 5L * 262144);
  wt_cvt<<<(256 * 1024 + 255) / 256, 256, 0, stream>>>(Wg0, Wg0t, 1008, 1024, 256);
  wt_cvt<<<(128 * 1024 + 255) / 256, 256, 0, stream>>>(Wc0, Wc0t, 1008, 1024, 128);
  wt_cvt<<<(256 * 1792 + 255) / 256, 256, 0, stream>>>(Wg1, Wg1t, 1792, 1792, 256);
  wt_cvt<<<(128 * 1792 + 255) / 256, 256, 0, stream>>>(Wc1, Wc1t, 1792, 1792, 128);

  // ---- prologue: L0 phase of step 0 ----
  xk<<<64, 256, 0, stream>>>(x_seq, 0, z0g, z0c, z0Tg);
  gemm_diff<128, 16, 4, 1><<<dim3(4, 1, 96), 256, 0, stream>>>(
      Tpow, z0Tg, z0g, 1024, 144, 0, z0c, 16);
  gproj2<<<512, 256, 0, stream>>>(                  // role1 slot = L0 gproj(0)
      z0g, 1024, z0g, 1024, Wg0t, 1024, bg0, h0, z0c, 1024, 16, z0Tc, ubuf0,
      z0g, Wg0t, bg0, h0, z0c, z0Tc, ubuf0);
  fused1<<<512, 256, 0, stream>>>(                   // L0f(0): h0(0) -> z0g+16, t0A+0
      z0c, z0c, 1024, z0c, 1024, Wc0t, 1024, bc0, ubuf0, h0, g0, be0,
      z0g, 1024, 16, t0A, 256, 0, z0Tg, 16, z1Tg, 0,
      x_seq, 1, z0g, z0c, z0Tg);

  // ---- skewed pipeline: iter s runs L1(s) merged with L0(s+1) ----
  for (int s = 0; s < 7; s++) {
    u16* t0c = (s & 1) ? t0B : t0A;
    u16* t0n = (s & 1) ? t0A : t0B;
    int y1sh = (s == 0) ? 1 : 2;
    int r1 = 4 * (1 << y1sh) * 96;
    gdiff2<<<r1 + 1152, 256, 0, stream>>>(
        Tpow, z1Tg, z1g, y1sh, r1, z0Tg, z0g, z0c);
    gproj2<<<1024, 256, 0, stream>>>(
        z1g, 1792, t0c, 256, Wg1t, 1792, bg1, h1, z1c, 1792, 128, z1Tc, ubuf1,
        z0g, Wg0t, bg0, h0, z0c, z0Tc, ubuf0);
    int c1 = (s == 0) ? 0 : 768;
    cdiff2<<<c1 + 768, 256, 0, stream>>>(
        Tpow, z1Tc, z1c, c1, z0Tc, z0c);
    fused2<<<512, 256, 0, stream>>>(
        z1g, z1c, 1792, t0c, 256, Wc1t, 1792, bc1, ubuf1, h1, g1, be1,
        t0n, 256, 128, z1Tg, 128,
        z0c, z0c, Wc0t, bc0, ubuf0, h0, g0, be0,
        z0g, 16, t0n, 256, 0, z0Tg, 16, z1Tg, 0,
        (s + 2 <= 7) ? x_seq : nullptr, s + 2, z0g, z0c, z0Tg);
  }

  // ---- epilogue: L1 phase of step 7 ----
  {
    u16* t0c = t0B;   // 7&1 = 1
    u16* t0n = t0A;
    gdiff2<<<1536, 256, 0, stream>>>(Tpow, z1Tg, z1g, 2, 1536, z0Tg, z0g, z0c);
    gproj2<<<512, 256, 0, stream>>>(
        z1g, 1792, t0c, 256, Wg1t, 1792, bg1, h1, z1c, 1792, 128, z1Tc, ubuf1,
        z0g, Wg0t, bg0, h0, z0c, z0Tc, ubuf0);
    cdiff2<<<768, 256, 0, stream>>>(Tpow, z1Tc, z1c, 768, z0Tc, z0c);
    fused1<<<512, 256, 0, stream>>>(
        z1g, z1c, 1792, t0c, 256, Wc1t, 1792, bc1, ubuf1, h1, g1, be1,
        t0n, 256, 128, nullptr, 0, 0, z1Tg, 128, nullptr, 0,
        nullptr, 0, nullptr, nullptr, nullptr);
  }
}